// Round 2
// baseline (1260.326 us; speedup 1.0000x reference)
//
#include <hip/hip_runtime.h>
#include <hip/hip_bf16.h>
#include <cstdint>
#include <cstddef>

typedef __bf16 bf16;
typedef __bf16 bf16x2 __attribute__((ext_vector_type(2)));
typedef __bf16 bf16x4 __attribute__((ext_vector_type(4)));
typedef __bf16 bf16x8 __attribute__((ext_vector_type(8)));
typedef float f32x4 __attribute__((ext_vector_type(4)));

// ---------------- constants ----------------
#define EDIM 2048
#define SEQ  2048
#define BATCH 2
#define NH   32
#define NKV  8
#define HD   64
#define FF   8192
#define NTOK 4096          // BATCH*SEQ
#define QKVN 3072          // EDIM + 2*512

// async 16B global -> LDS (lane-contiguous LDS layout required)
__device__ __forceinline__ void gld_lds16(const void* gp, void* lp) {
    __builtin_amdgcn_global_load_lds(
        (__attribute__((address_space(1))) void*)(gp),
        (__attribute__((address_space(3))) void*)(lp), 16, 0, 0);
}

// ---------------- fp32 -> bf16 convert ----------------
__global__ __launch_bounds__(256)
void cvt_f32_bf16(const float* __restrict__ in, bf16* __restrict__ out, long n4) {
    long i = (long)blockIdx.x * blockDim.x + threadIdx.x;
    long stride = (long)gridDim.x * blockDim.x;
    for (; i < n4; i += stride) {
        float4 v = ((const float4*)in)[i];
        bf16x4 o;
        o[0] = (bf16)v.x; o[1] = (bf16)v.y; o[2] = (bf16)v.z; o[3] = (bf16)v.w;
        ((bf16x4*)out)[i] = o;
    }
}

// ---------------- RMSNorm: fp32 row -> bf16 row ----------------
__global__ __launch_bounds__(256)
void rmsnorm_bf16(const float* __restrict__ x, const float* __restrict__ w,
                  bf16* __restrict__ out) {
    __shared__ float red[4];
    const int row = blockIdx.x;
    const long base = (long)row * EDIM;
    const int t = threadIdx.x;
    float4 v0 = *(const float4*)(x + base + t * 4);
    float4 v1 = *(const float4*)(x + base + 1024 + t * 4);
    float ss = v0.x*v0.x + v0.y*v0.y + v0.z*v0.z + v0.w*v0.w
             + v1.x*v1.x + v1.y*v1.y + v1.z*v1.z + v1.w*v1.w;
    #pragma unroll
    for (int off = 1; off < 64; off <<= 1) ss += __shfl_xor(ss, off, 64);
    if ((t & 63) == 0) red[t >> 6] = ss;
    __syncthreads();
    float tot = red[0] + red[1] + red[2] + red[3];
    float inv = rsqrtf(tot * (1.0f / EDIM) + 1e-5f);
    float4 w0 = *(const float4*)(w + t * 4);
    float4 w1 = *(const float4*)(w + 1024 + t * 4);
    bf16x4 o0, o1;
    o0[0] = (bf16)(v0.x * inv * w0.x); o0[1] = (bf16)(v0.y * inv * w0.y);
    o0[2] = (bf16)(v0.z * inv * w0.z); o0[3] = (bf16)(v0.w * inv * w0.w);
    o1[0] = (bf16)(v1.x * inv * w1.x); o1[1] = (bf16)(v1.y * inv * w1.y);
    o1[2] = (bf16)(v1.z * inv * w1.z); o1[3] = (bf16)(v1.w * inv * w1.w);
    *(bf16x4*)(out + base + t * 4) = o0;
    *(bf16x4*)(out + base + 1024 + t * 4) = o1;
}

// ---------------- NT GEMM: C[M,N] = A[M,K] * B[N,K]^T ----------------
// m97 structure: 128x128 tile, BK=32, 4 waves, 4x4 of mfma_f32_16x16x32_bf16
// EPI: 0 = f32 store, 1 = bf16 store, 2 = f32 store + f32 residual add,
//      3 = bf16 in-place: Cv[idx] = silu(Cv[idx]) * acc   (SwiGLU fuse)
template<int EPI>
__global__ __launch_bounds__(256, 2)
void gemm_nt(const bf16* __restrict__ A, const bf16* __restrict__ B,
             void* __restrict__ Cv, const float* __restrict__ res,
             int M, int N, int K) {
    __shared__ bf16 As[128 * 32];
    __shared__ bf16 Bs[128 * 32];
    const int tid = threadIdx.x;
    const int lane = tid & 63;
    const int wave = tid >> 6;
    const int wm = (wave >> 1) * 64;
    const int wn = (wave & 1) * 64;
    const int bm = blockIdx.y * 128;
    const int bn = blockIdx.x * 128;
    const int lrow = lane & 15;
    const int koff = (lane >> 4) * 8;

    f32x4 acc[4][4] = {};

    for (int k0 = 0; k0 < K; k0 += 32) {
        __syncthreads();
        #pragma unroll
        for (int t = 0; t < 2; ++t) {
            int c = tid + t * 256;           // 512 chunks of 16B per tile
            int r = c >> 2;
            int kc = (c & 3) * 8;
            gld_lds16(A + (long)(bm + r) * K + k0 + kc, As + c * 8);
            gld_lds16(B + (long)(bn + r) * K + k0 + kc, Bs + c * 8);
        }
        __syncthreads();
        bf16x8 af[4], bfr[4];
        #pragma unroll
        for (int t = 0; t < 4; ++t) {
            af[t]  = *(const bf16x8*)(As + (wm + t * 16 + lrow) * 32 + koff);
            bfr[t] = *(const bf16x8*)(Bs + (wn + t * 16 + lrow) * 32 + koff);
        }
        #pragma unroll
        for (int i = 0; i < 4; ++i)
            #pragma unroll
            for (int j = 0; j < 4; ++j)
                acc[i][j] = __builtin_amdgcn_mfma_f32_16x16x32_bf16(af[i], bfr[j], acc[i][j], 0, 0, 0);
    }

    const int row0 = bm + wm + (lane >> 4) * 4;
    const int col0 = bn + wn + (lane & 15);
    #pragma unroll
    for (int i = 0; i < 4; ++i) {
        #pragma unroll
        for (int j = 0; j < 4; ++j) {
            int col = col0 + j * 16;
            #pragma unroll
            for (int r = 0; r < 4; ++r) {
                long idx = (long)(row0 + i * 16 + r) * N + col;
                float v = acc[i][j][r];
                if (EPI == 0) {
                    ((float*)Cv)[idx] = v;
                } else if (EPI == 1) {
                    ((bf16*)Cv)[idx] = (bf16)v;
                } else if (EPI == 2) {
                    ((float*)Cv)[idx] = v + res[idx];
                } else {                       // EPI == 3: SwiGLU in-place
                    float u = (float)((bf16*)Cv)[idx];
                    float sl = u / (1.0f + __expf(-u));
                    ((bf16*)Cv)[idx] = (bf16)(sl * v);
                }
            }
        }
    }
}

// ---------------- RoPE prep: qkv bf16 [4096,3072] -> Q [B,H,S,64], K [B,KH,S,64] ----------------
__global__ __launch_bounds__(256)
void rope_prep(const bf16* __restrict__ qkv, const float* __restrict__ fr,
               bf16* __restrict__ Qo, bf16* __restrict__ Ko) {
    const int row = blockIdx.x;            // b*SEQ + s
    const int b = row >> 11, s = row & 2047;
    const int t = threadIdx.x;
    const long rbase = (long)row * QKVN;
    #pragma unroll
    for (int i = 0; i < 4; ++i) {          // 1024 q pairs
        int p = t + i * 256;
        int hh = p >> 5, d = p & 31;
        bf16x2 xv = *(const bf16x2*)(qkv + rbase + hh * 64 + 2 * d);
        float x0 = (float)xv[0], x1 = (float)xv[1];
        float2 cs = *(const float2*)(fr + (long)(s * 32 + d) * 2);
        bf16x2 o;
        o[0] = (bf16)(x0 * cs.x - x1 * cs.y);
        o[1] = (bf16)(x1 * cs.x + x0 * cs.y);
        *(bf16x2*)(Qo + ((long)(b * NH + hh) * SEQ + s) * HD + 2 * d) = o;
    }
    {                                       // 256 k pairs
        int kh = t >> 5, d = t & 31;
        bf16x2 xv = *(const bf16x2*)(qkv + rbase + EDIM + kh * 64 + 2 * d);
        float x0 = (float)xv[0], x1 = (float)xv[1];
        float2 cs = *(const float2*)(fr + (long)(s * 32 + d) * 2);
        bf16x2 o;
        o[0] = (bf16)(x0 * cs.x - x1 * cs.y);
        o[1] = (bf16)(x1 * cs.x + x0 * cs.y);
        *(bf16x2*)(Ko + ((long)(b * NKV + kh) * SEQ + s) * HD + 2 * d) = o;
    }
}

// ---------------- V prep: transpose into [B,KH,S/64,hd=64,kk=64] bf16 tiles ----------------
__global__ __launch_bounds__(256)
void v_prep(const bf16* __restrict__ qkv, bf16* __restrict__ Vt) {
    __shared__ bf16 tile[64 * 72];          // +8 pad to break transpose conflicts
    const int blk = blockIdx.x;             // b*256 + kvh*32 + st
    const int b = blk >> 8;
    const int kvh = (blk >> 5) & 7;
    const int st = blk & 31;
    const int t = threadIdx.x;
    #pragma unroll
    for (int i = 0; i < 2; ++i) {
        int c = t + i * 256;                // 512 chunks
        int kk = c >> 3, hdo = (c & 7) * 8;
        bf16x8 v = *(const bf16x8*)(qkv + (long)(b * SEQ + st * 64 + kk) * QKVN + 2560 + kvh * 64 + hdo);
        *(bf16x8*)(tile + kk * 72 + hdo) = v;
    }
    __syncthreads();
    const long obase = ((long)(b * NKV + kvh) * 32 + st) * 4096;
    #pragma unroll
    for (int i = 0; i < 2; ++i) {
        int c = t + i * 256;
        int hd = c >> 3, ko = (c & 7) * 8;
        bf16x8 v;
        #pragma unroll
        for (int j = 0; j < 8; ++j) v[j] = tile[(ko + j) * 72 + hd];
        *(bf16x8*)(Vt + obase + hd * 64 + ko) = v;
    }
}

// ---------------- flash attention (causal, GQA 4:1) ----------------
// block = (q-tile of 64) x (b,h); 4 waves, each 16 q-rows x 64 hd
__global__ __launch_bounds__(256, 2)
void attn_fwd(const bf16* __restrict__ Q, const bf16* __restrict__ K,
              const bf16* __restrict__ Vt, bf16* __restrict__ Out) {
    __shared__ bf16 Qs[64 * 64];
    __shared__ bf16 Ks[64 * 64];
    __shared__ bf16 Vs[64 * 64];
    __shared__ bf16 Ps[4 * 16 * 64];
    const int tid = threadIdx.x, lane = tid & 63, w = tid >> 6;
    const int qt = blockIdx.x;
    const int bh = blockIdx.y;
    const int b = bh >> 5, h = bh & 31;
    const int kvh = h >> 2;
    const long qbase  = ((long)(b * NH + h) * SEQ + qt * 64) * HD;
    const long kbase  = ((long)(b * NKV + kvh) * SEQ) * HD;
    const long vbase  = ((long)(b * NKV + kvh) * 32) * 4096;
    const int lrow = lane & 15, koff = (lane >> 4) * 8;
    const int qrow = (lane >> 4) * 4;           // + r
    const int q_glob0 = qt * 64 + w * 16 + qrow;

    #pragma unroll
    for (int t = 0; t < 2; ++t) {
        int c = tid + t * 256;
        gld_lds16(Q + qbase + c * 8, Qs + c * 8);
    }
    __syncthreads();
    bf16x8 qa0 = *(const bf16x8*)(Qs + (w * 16 + lrow) * 64 + koff);
    bf16x8 qa1 = *(const bf16x8*)(Qs + (w * 16 + lrow) * 64 + 32 + koff);

    f32x4 acc_o[4] = {};
    float m_i[4], l_i[4];
    #pragma unroll
    for (int r = 0; r < 4; ++r) { m_i[r] = -1e30f; l_i[r] = 0.f; }

    for (int kt = 0; kt <= qt; ++kt) {
        __syncthreads();                       // prior iter's LDS reads done
        #pragma unroll
        for (int t = 0; t < 2; ++t) {
            int c = tid + t * 256;
            gld_lds16(K  + kbase + (long)kt * 4096 + c * 8, Ks + c * 8);
            gld_lds16(Vt + vbase + (long)kt * 4096 + c * 8, Vs + c * 8);
        }
        __syncthreads();                       // staging visible

        f32x4 s[4];
        #pragma unroll
        for (int nt = 0; nt < 4; ++nt) {
            bf16x8 kb0 = *(const bf16x8*)(Ks + (nt * 16 + lrow) * 64 + koff);
            bf16x8 kb1 = *(const bf16x8*)(Ks + (nt * 16 + lrow) * 64 + 32 + koff);
            f32x4 z = {};
            z = __builtin_amdgcn_mfma_f32_16x16x32_bf16(qa0, kb0, z, 0, 0, 0);
            z = __builtin_amdgcn_mfma_f32_16x16x32_bf16(qa1, kb1, z, 0, 0, 0);
            s[nt] = z * 0.125f;
        }
        if (kt == qt) {
            #pragma unroll
            for (int nt = 0; nt < 4; ++nt) {
                int kk = qt * 64 + nt * 16 + lrow;
                #pragma unroll
                for (int r = 0; r < 4; ++r)
                    if (kk > q_glob0 + r) s[nt][r] = -1e30f;
            }
        }
        float mnew[4], alpha[4], rs[4];
        #pragma unroll
        for (int r = 0; r < 4; ++r) {
            float mx = fmaxf(fmaxf(s[0][r], s[1][r]), fmaxf(s[2][r], s[3][r]));
            #pragma unroll
            for (int off = 1; off < 16; off <<= 1)
                mx = fmaxf(mx, __shfl_xor(mx, off, 64));
            mnew[r] = fmaxf(m_i[r], mx);
            alpha[r] = __expf(m_i[r] - mnew[r]);
            m_i[r] = mnew[r];
            rs[r] = 0.f;
        }
        #pragma unroll
        for (int nt = 0; nt < 4; ++nt)
            #pragma unroll
            for (int r = 0; r < 4; ++r) {
                float p = __expf(s[nt][r] - mnew[r]);
                s[nt][r] = p;
                rs[r] += p;
            }
        #pragma unroll
        for (int r = 0; r < 4; ++r) {
            #pragma unroll
            for (int off = 1; off < 16; off <<= 1)
                rs[r] += __shfl_xor(rs[r], off, 64);
            l_i[r] = l_i[r] * alpha[r] + rs[r];
            #pragma unroll
            for (int nt = 0; nt < 4; ++nt) acc_o[nt][r] *= alpha[r];
        }
        // P (C-layout) -> LDS -> A-layout
        bf16* Pw = Ps + w * 16 * 64;
        #pragma unroll
        for (int nt = 0; nt < 4; ++nt)
            #pragma unroll
            for (int r = 0; r < 4; ++r)
                Pw[(qrow + r) * 64 + nt * 16 + lrow] = (bf16)s[nt][r];
        __syncthreads();                       // P visible (and lgkm drained)
        bf16x8 pa0 = *(const bf16x8*)(Pw + lrow * 64 + koff);
        bf16x8 pa1 = *(const bf16x8*)(Pw + lrow * 64 + 32 + koff);
        #pragma unroll
        for (int nt = 0; nt < 4; ++nt) {
            bf16x8 vb0 = *(const bf16x8*)(Vs + (nt * 16 + lrow) * 64 + koff);
            bf16x8 vb1 = *(const bf16x8*)(Vs + (nt * 16 + lrow) * 64 + 32 + koff);
            acc_o[nt] = __builtin_amdgcn_mfma_f32_16x16x32_bf16(pa0, vb0, acc_o[nt], 0, 0, 0);
            acc_o[nt] = __builtin_amdgcn_mfma_f32_16x16x32_bf16(pa1, vb1, acc_o[nt], 0, 0, 0);
        }
        __syncthreads();                       // PV reads done before restage
    }

    const long obase = ((long)b * SEQ + qt * 64) * EDIM + h * 64;
    #pragma unroll
    for (int nt = 0; nt < 4; ++nt) {
        #pragma unroll
        for (int r = 0; r < 4; ++r) {
            float v = acc_o[nt][r] / l_i[r];
            Out[obase + (long)(w * 16 + qrow + r) * EDIM + nt * 16 + lrow] = (bf16)v;
        }
    }
}

// ---------------- launcher ----------------
extern "C" void kernel_launch(void* const* d_in, const int* in_sizes, int n_in,
                              void* d_out, int out_size, void* d_ws, size_t ws_size,
                              hipStream_t stream) {
    const float* x    = (const float*)d_in[0];
    // d_in[1] = attention_mask (always causal tril; handled analytically)
    const float* fr   = (const float*)d_in[2];
    const float* wqkv = (const float*)d_in[3];
    const float* wo   = (const float*)d_in[4];
    const float* w1   = (const float*)d_in[5];
    const float* w2   = (const float*)d_in[6];
    const float* w3   = (const float*)d_in[7];
    const float* anw  = (const float*)d_in[8];
    const float* fnw  = (const float*)d_in[9];
    float* out = (float*)d_out;

    // ---- workspace budget (aliased layout), ~252 MiB ----
    const size_t SZ_WQKV = (size_t)QKVN * EDIM;     // 6291456
    const size_t SZ_WO   = (size_t)EDIM * EDIM;     // 4194304
    const size_t SZ_WFF  = (size_t)FF * EDIM;       // 16777216
    const size_t B_WQKV  = SZ_WQKV * 2;             // 12.6 MB
    const size_t B_WO    = SZ_WO * 2;               //  8.4 MB
    const size_t B_WFF   = SZ_WFF * 2;              // 33.6 MB
    const size_t B_HATTN = (size_t)NTOK * EDIM * 2; // 16.8 MB
    const size_t B_QKV   = (size_t)NTOK * QKVN * 2; // 25.2 MB
    const size_t B_SCR   = (size_t)NTOK * EDIM * 4; // 33.6 MB (h2 fp32; aliases Q/K/Vt)
    const size_t B_FF1   = (size_t)NTOK * FF * 2;   // 67.1 MB
    const size_t NEED = B_WQKV + B_WO + 3 * B_WFF + B_HATTN + B_QKV + B_SCR + B_FF1;
    if (ws_size < NEED) return;   // diagnostic: clean absmax-fail instead of GPU fault

    char* ws = (char*)d_ws;
    size_t off = 0;
    auto alloc = [&](size_t bytes) -> void* {
        void* p = ws + off;
        off += (bytes + 255) & ~(size_t)255;
        return p;
    };
    bf16* wqkv_b = (bf16*)alloc(B_WQKV);
    bf16* wo_b   = (bf16*)alloc(B_WO);
    bf16* w1_b   = (bf16*)alloc(B_WFF);
    bf16* w3_b   = (bf16*)alloc(B_WFF);
    bf16* w2_b   = (bf16*)alloc(B_WFF);
    bf16* h_attn = (bf16*)alloc(B_HATTN);           // h, then attn_out
    bf16* qkv_g  = (bf16*)alloc(B_QKV);             // qkv, then g
    char* scr    = (char*)alloc(B_SCR);             // Q/K/Vt region, then h2
    bf16* Qb  = (bf16*)scr;                                         // 16.8 MB
    bf16* Kb  = (bf16*)(scr + (size_t)BATCH * NH * SEQ * HD * 2);   //  4.2 MB
    bf16* Vtb = (bf16*)(scr + (size_t)BATCH * (NH + NKV) * SEQ * HD * 2); // 4.2 MB
    float* h2 = (float*)scr;                        // aliases Q/K/Vt (dead by then)
    bf16* ff1 = (bf16*)alloc(B_FF1);                // u, then act (in-place SwiGLU)
    bf16* g_b = qkv_g;                              // reuse (qkv dead after preps)

    // 1. weights -> bf16
    cvt_f32_bf16<<<512, 256, 0, stream>>>(wqkv, wqkv_b, (long)(SZ_WQKV / 4));
    cvt_f32_bf16<<<512, 256, 0, stream>>>(wo,   wo_b,   (long)(SZ_WO / 4));
    cvt_f32_bf16<<<512, 256, 0, stream>>>(w1,   w1_b,   (long)(SZ_WFF / 4));
    cvt_f32_bf16<<<512, 256, 0, stream>>>(w3,   w3_b,   (long)(SZ_WFF / 4));
    cvt_f32_bf16<<<512, 256, 0, stream>>>(w2,   w2_b,   (long)(SZ_WFF / 4));
    // 2. h = rmsnorm(x) * attn_norm_w  (bf16)
    rmsnorm_bf16<<<NTOK, 256, 0, stream>>>(x, anw, h_attn);
    // 3. qkv = h @ w_qkv^T  (bf16 out)
    gemm_nt<1><<<dim3(QKVN / 128, NTOK / 128), 256, 0, stream>>>(
        h_attn, wqkv_b, qkv_g, nullptr, NTOK, QKVN, EDIM);
    // 4. RoPE + layout prep
    rope_prep<<<NTOK, 256, 0, stream>>>(qkv_g, fr, Qb, Kb);
    v_prep<<<BATCH * NKV * (SEQ / 64), 256, 0, stream>>>(qkv_g, Vtb);
    // 5. attention -> attn_out (bf16, [4096,2048])
    attn_fwd<<<dim3(SEQ / 64, BATCH * NH), 256, 0, stream>>>(Qb, Kb, Vtb, h_attn);
    // 6. h2 = x + attn_out @ w_o^T  (fp32; h2 aliases dead Q/K/Vt)
    gemm_nt<2><<<dim3(EDIM / 128, NTOK / 128), 256, 0, stream>>>(
        h_attn, wo_b, h2, x, NTOK, EDIM, EDIM);
    // 7. g = rmsnorm(h2) * ff_norm_w (bf16)
    rmsnorm_bf16<<<NTOK, 256, 0, stream>>>(h2, fnw, g_b);
    // 8. u = g @ w1^T (bf16), then act = silu(u) * (g @ w3^T) in-place over ff1
    gemm_nt<1><<<dim3(FF / 128, NTOK / 128), 256, 0, stream>>>(
        g_b, w1_b, ff1, nullptr, NTOK, FF, EDIM);
    gemm_nt<3><<<dim3(FF / 128, NTOK / 128), 256, 0, stream>>>(
        g_b, w3_b, ff1, nullptr, NTOK, FF, EDIM);
    // 9. out = h2 + act @ w2^T  (fp32)
    gemm_nt<2><<<dim3(EDIM / 128, NTOK / 128), 256, 0, stream>>>(
        ff1, w2_b, out, h2, NTOK, EDIM, FF);
    (void)in_sizes; (void)n_in; (void)out_size; (void)ws_size;
}

// Round 3
// 1209.344 us; speedup vs baseline: 1.0422x; 1.0422x over previous
//
#include <hip/hip_runtime.h>
#include <hip/hip_bf16.h>
#include <cstdint>
#include <cstddef>

typedef __bf16 bf16;
typedef __bf16 bf16x2 __attribute__((ext_vector_type(2)));
typedef __bf16 bf16x4 __attribute__((ext_vector_type(4)));
typedef __bf16 bf16x8 __attribute__((ext_vector_type(8)));
typedef float f32x4 __attribute__((ext_vector_type(4)));

// ---------------- constants ----------------
#define EDIM 2048
#define SEQ  2048
#define BATCH 2
#define NH   32
#define NKV  8
#define HD   64
#define FF   8192
#define NTOK 4096          // BATCH*SEQ
#define QKVN 3072          // EDIM + 2*512

// async 16B global -> LDS (lane-contiguous LDS layout required)
__device__ __forceinline__ void gld_lds16(const void* gp, void* lp) {
    __builtin_amdgcn_global_load_lds(
        (__attribute__((address_space(1))) void*)(gp),
        (__attribute__((address_space(3))) void*)(lp), 16, 0, 0);
}

// ---------------- fp32 -> bf16 convert ----------------
__global__ __launch_bounds__(256)
void cvt_f32_bf16(const float* __restrict__ in, bf16* __restrict__ out, long n4) {
    long i = (long)blockIdx.x * blockDim.x + threadIdx.x;
    long stride = (long)gridDim.x * blockDim.x;
    for (; i < n4; i += stride) {
        float4 v = ((const float4*)in)[i];
        bf16x4 o;
        o[0] = (bf16)v.x; o[1] = (bf16)v.y; o[2] = (bf16)v.z; o[3] = (bf16)v.w;
        ((bf16x4*)out)[i] = o;
    }
}

// ---------------- RMSNorm: fp32 row -> bf16 row ----------------
__global__ __launch_bounds__(256)
void rmsnorm_bf16(const float* __restrict__ x, const float* __restrict__ w,
                  bf16* __restrict__ out) {
    __shared__ float red[4];
    const int row = blockIdx.x;
    const long base = (long)row * EDIM;
    const int t = threadIdx.x;
    float4 v0 = *(const float4*)(x + base + t * 4);
    float4 v1 = *(const float4*)(x + base + 1024 + t * 4);
    float ss = v0.x*v0.x + v0.y*v0.y + v0.z*v0.z + v0.w*v0.w
             + v1.x*v1.x + v1.y*v1.y + v1.z*v1.z + v1.w*v1.w;
    #pragma unroll
    for (int off = 1; off < 64; off <<= 1) ss += __shfl_xor(ss, off, 64);
    if ((t & 63) == 0) red[t >> 6] = ss;
    __syncthreads();
    float tot = red[0] + red[1] + red[2] + red[3];
    float inv = rsqrtf(tot * (1.0f / EDIM) + 1e-5f);
    float4 w0 = *(const float4*)(w + t * 4);
    float4 w1 = *(const float4*)(w + 1024 + t * 4);
    bf16x4 o0, o1;
    o0[0] = (bf16)(v0.x * inv * w0.x); o0[1] = (bf16)(v0.y * inv * w0.y);
    o0[2] = (bf16)(v0.z * inv * w0.z); o0[3] = (bf16)(v0.w * inv * w0.w);
    o1[0] = (bf16)(v1.x * inv * w1.x); o1[1] = (bf16)(v1.y * inv * w1.y);
    o1[2] = (bf16)(v1.z * inv * w1.z); o1[3] = (bf16)(v1.w * inv * w1.w);
    *(bf16x4*)(out + base + t * 4) = o0;
    *(bf16x4*)(out + base + 1024 + t * 4) = o1;
}

// ---------------- NT GEMM: C[M,N] = A[M,K] * B[N,K]^T ----------------
// m97 structure: 128x128 tile, BK=32, 4 waves, 4x4 of mfma_f32_16x16x32_bf16
// EPI: 0 = f32 store, 1 = bf16 store, 2 = f32 store + f32 residual add,
//      3 = bf16 in-place: Cv[idx] = silu(Cv[idx]) * acc   (SwiGLU fuse)
template<int EPI>
__global__ __launch_bounds__(256, 2)
void gemm_nt(const bf16* __restrict__ A, const bf16* __restrict__ B,
             void* __restrict__ Cv, const float* __restrict__ res,
             int M, int N, int K) {
    __shared__ bf16 As[128 * 32];
    __shared__ bf16 Bs[128 * 32];
    const int tid = threadIdx.x;
    const int lane = tid & 63;
    const int wave = tid >> 6;
    const int wm = (wave >> 1) * 64;
    const int wn = (wave & 1) * 64;
    const int bm = blockIdx.y * 128;
    const int bn = blockIdx.x * 128;
    const int lrow = lane & 15;
    const int koff = (lane >> 4) * 8;

    f32x4 acc[4][4] = {};

    for (int k0 = 0; k0 < K; k0 += 32) {
        __syncthreads();
        #pragma unroll
        for (int t = 0; t < 2; ++t) {
            int c = tid + t * 256;           // 512 chunks of 16B per tile
            int r = c >> 2;
            int kc = (c & 3) * 8;
            gld_lds16(A + (long)(bm + r) * K + k0 + kc, As + c * 8);
            gld_lds16(B + (long)(bn + r) * K + k0 + kc, Bs + c * 8);
        }
        __syncthreads();
        bf16x8 af[4], bfr[4];
        #pragma unroll
        for (int t = 0; t < 4; ++t) {
            af[t]  = *(const bf16x8*)(As + (wm + t * 16 + lrow) * 32 + koff);
            bfr[t] = *(const bf16x8*)(Bs + (wn + t * 16 + lrow) * 32 + koff);
        }
        #pragma unroll
        for (int i = 0; i < 4; ++i)
            #pragma unroll
            for (int j = 0; j < 4; ++j)
                acc[i][j] = __builtin_amdgcn_mfma_f32_16x16x32_bf16(af[i], bfr[j], acc[i][j], 0, 0, 0);
    }

    const int row0 = bm + wm + (lane >> 4) * 4;
    const int col0 = bn + wn + (lane & 15);
    #pragma unroll
    for (int i = 0; i < 4; ++i) {
        #pragma unroll
        for (int j = 0; j < 4; ++j) {
            int col = col0 + j * 16;
            #pragma unroll
            for (int r = 0; r < 4; ++r) {
                long idx = (long)(row0 + i * 16 + r) * N + col;
                float v = acc[i][j][r];
                if (EPI == 0) {
                    ((float*)Cv)[idx] = v;
                } else if (EPI == 1) {
                    ((bf16*)Cv)[idx] = (bf16)v;
                } else if (EPI == 2) {
                    ((float*)Cv)[idx] = v + res[idx];
                } else {                       // EPI == 3: SwiGLU in-place
                    float u = (float)((bf16*)Cv)[idx];
                    float sl = u / (1.0f + __expf(-u));
                    ((bf16*)Cv)[idx] = (bf16)(sl * v);
                }
            }
        }
    }
}

// ---------------- RoPE prep: qkv bf16 [4096,3072] -> Q [B,H,S,64], K [B,KH,S,64] ----------------
__global__ __launch_bounds__(256)
void rope_prep(const bf16* __restrict__ qkv, const float* __restrict__ fr,
               bf16* __restrict__ Qo, bf16* __restrict__ Ko) {
    const int row = blockIdx.x;            // b*SEQ + s
    const int b = row >> 11, s = row & 2047;
    const int t = threadIdx.x;
    const long rbase = (long)row * QKVN;
    #pragma unroll
    for (int i = 0; i < 4; ++i) {          // 1024 q pairs
        int p = t + i * 256;
        int hh = p >> 5, d = p & 31;
        bf16x2 xv = *(const bf16x2*)(qkv + rbase + hh * 64 + 2 * d);
        float x0 = (float)xv[0], x1 = (float)xv[1];
        float2 cs = *(const float2*)(fr + (long)(s * 32 + d) * 2);
        bf16x2 o;
        o[0] = (bf16)(x0 * cs.x - x1 * cs.y);
        o[1] = (bf16)(x1 * cs.x + x0 * cs.y);
        *(bf16x2*)(Qo + ((long)(b * NH + hh) * SEQ + s) * HD + 2 * d) = o;
    }
    {                                       // 256 k pairs
        int kh = t >> 5, d = t & 31;
        bf16x2 xv = *(const bf16x2*)(qkv + rbase + EDIM + kh * 64 + 2 * d);
        float x0 = (float)xv[0], x1 = (float)xv[1];
        float2 cs = *(const float2*)(fr + (long)(s * 32 + d) * 2);
        bf16x2 o;
        o[0] = (bf16)(x0 * cs.x - x1 * cs.y);
        o[1] = (bf16)(x1 * cs.x + x0 * cs.y);
        *(bf16x2*)(Ko + ((long)(b * NKV + kh) * SEQ + s) * HD + 2 * d) = o;
    }
}

// ---------------- V prep: transpose into [B,KH,S/64,hd=64,kk=64] bf16 tiles ----------------
__global__ __launch_bounds__(256)
void v_prep(const bf16* __restrict__ qkv, bf16* __restrict__ Vt) {
    __shared__ bf16 tile[64 * 72];          // +8 pad to break transpose conflicts
    const int blk = blockIdx.x;             // b*256 + kvh*32 + st
    const int b = blk >> 8;
    const int kvh = (blk >> 5) & 7;
    const int st = blk & 31;
    const int t = threadIdx.x;
    #pragma unroll
    for (int i = 0; i < 2; ++i) {
        int c = t + i * 256;                // 512 chunks
        int kk = c >> 3, hdo = (c & 7) * 8;
        bf16x8 v = *(const bf16x8*)(qkv + (long)(b * SEQ + st * 64 + kk) * QKVN + 2560 + kvh * 64 + hdo);
        *(bf16x8*)(tile + kk * 72 + hdo) = v;
    }
    __syncthreads();
    const long obase = ((long)(b * NKV + kvh) * 32 + st) * 4096;
    #pragma unroll
    for (int i = 0; i < 2; ++i) {
        int c = t + i * 256;
        int hd = c >> 3, ko = (c & 7) * 8;
        bf16x8 v;
        #pragma unroll
        for (int j = 0; j < 8; ++j) v[j] = tile[(ko + j) * 72 + hd];
        *(bf16x8*)(Vt + obase + hd * 64 + ko) = v;
    }
}

// ---------------- flash attention (causal, GQA 4:1), barrier-free ----------------
// block = 128 q-rows x (b,h); 4 waves, each wave owns 32 q-rows independently.
// K/V fragments load directly global->VGPR (L1/L2 reuse); only LDS use is the
// per-wave P transpose buffer with XOR-8 swizzle (conflict-free b128 reads).
__global__ __launch_bounds__(256)
void attn_fwd(const bf16* __restrict__ Q, const bf16* __restrict__ K,
              const bf16* __restrict__ Vt, bf16* __restrict__ Out) {
    __shared__ bf16 Ps[4 * 32 * 64];
    const int tid = threadIdx.x, lane = tid & 63, w = tid >> 6;
    const int qt = blockIdx.x;               // 128-row q tile
    const int bh = blockIdx.y;
    const int b = bh >> 5, h = bh & 31;
    const int kvh = h >> 2;
    const int g = lane >> 4, lrow = lane & 15;
    const int qrow = g * 4;
    const long qbase  = ((long)(b * NH + h) * SEQ + qt * 128 + w * 32) * HD;
    const long kvbase = ((long)(b * NKV + kvh) * SEQ) * HD;
    bf16* Pw = Ps + w * (32 * 64);

    bf16x8 qa[2][2];
    #pragma unroll
    for (int m = 0; m < 2; ++m)
        #pragma unroll
        for (int hf = 0; hf < 2; ++hf)
            qa[m][hf] = *(const bf16x8*)(Q + qbase + (long)(m * 16 + lrow) * HD + hf * 32 + g * 8);

    f32x4 acc[2][4] = {};
    float mi[2][4], li[2][4];
    #pragma unroll
    for (int m = 0; m < 2; ++m)
        #pragma unroll
        for (int r = 0; r < 4; ++r) { mi[m][r] = -1e30f; li[m][r] = 0.f; }

    const int ntiles = qt * 2 + (w >> 1) + 1;   // per-wave causal trip count

    for (int kt = 0; kt < ntiles; ++kt) {
        const bf16* Kt  = K  + kvbase + (long)kt * (64 * HD);
        const bf16* Vtt = Vt + kvbase + (long)kt * (64 * HD);

        f32x4 s[2][4];
        #pragma unroll
        for (int nt = 0; nt < 4; ++nt) {
            bf16x8 kb0 = *(const bf16x8*)(Kt + (nt * 16 + lrow) * HD + g * 8);
            bf16x8 kb1 = *(const bf16x8*)(Kt + (nt * 16 + lrow) * HD + 32 + g * 8);
            #pragma unroll
            for (int m = 0; m < 2; ++m) {
                f32x4 z = {};
                z = __builtin_amdgcn_mfma_f32_16x16x32_bf16(qa[m][0], kb0, z, 0, 0, 0);
                z = __builtin_amdgcn_mfma_f32_16x16x32_bf16(qa[m][1], kb1, z, 0, 0, 0);
                s[m][nt] = z * 0.125f;
            }
        }
        if (kt == ntiles - 1) {
            #pragma unroll
            for (int nt = 0; nt < 4; ++nt) {
                int kk = kt * 64 + nt * 16 + lrow;
                #pragma unroll
                for (int m = 0; m < 2; ++m) {
                    int q0 = qt * 128 + w * 32 + m * 16 + qrow;
                    #pragma unroll
                    for (int r = 0; r < 4; ++r)
                        if (kk > q0 + r) s[m][nt][r] = -1e30f;
                }
            }
        }
        #pragma unroll
        for (int m = 0; m < 2; ++m) {
            #pragma unroll
            for (int r = 0; r < 4; ++r) {
                float mx = fmaxf(fmaxf(s[m][0][r], s[m][1][r]), fmaxf(s[m][2][r], s[m][3][r]));
                #pragma unroll
                for (int off = 1; off < 16; off <<= 1)
                    mx = fmaxf(mx, __shfl_xor(mx, off, 64));
                float mnew = fmaxf(mi[m][r], mx);
                float alpha = __expf(mi[m][r] - mnew);
                mi[m][r] = mnew;
                float rs = 0.f;
                #pragma unroll
                for (int nt = 0; nt < 4; ++nt) {
                    float p = __expf(s[m][nt][r] - mnew);
                    s[m][nt][r] = p;
                    rs += p;
                }
                #pragma unroll
                for (int off = 1; off < 16; off <<= 1)
                    rs += __shfl_xor(rs, off, 64);
                li[m][r] = li[m][r] * alpha + rs;
                #pragma unroll
                for (int nt = 0; nt < 4; ++nt) acc[m][nt][r] *= alpha;
            }
        }
        // P: C-layout regs -> XOR-8 swizzled per-wave LDS -> A-layout frags.
        // slot(row,col) = row*64 + ((col>>3) ^ (row&7))*8 + (col&7)
        #pragma unroll
        for (int m = 0; m < 2; ++m)
            #pragma unroll
            for (int nt = 0; nt < 4; ++nt) {
                int cb = nt * 2 + (lrow >> 3);
                #pragma unroll
                for (int r = 0; r < 4; ++r) {
                    int row = m * 16 + qrow + r;
                    Pw[row * 64 + ((cb ^ (row & 7)) << 3) + (lrow & 7)] = (bf16)s[m][nt][r];
                }
            }
        bf16x8 pa[2][2];
        #pragma unroll
        for (int m = 0; m < 2; ++m)
            #pragma unroll
            for (int hf = 0; hf < 2; ++hf) {
                int row = m * 16 + lrow;
                int cbs = (hf * 4 + g) ^ (row & 7);
                pa[m][hf] = *(const bf16x8*)(Pw + row * 64 + cbs * 8);
            }
        #pragma unroll
        for (int nt = 0; nt < 4; ++nt) {
            bf16x8 vb0 = *(const bf16x8*)(Vtt + (nt * 16 + lrow) * HD + g * 8);
            bf16x8 vb1 = *(const bf16x8*)(Vtt + (nt * 16 + lrow) * HD + 32 + g * 8);
            #pragma unroll
            for (int m = 0; m < 2; ++m) {
                acc[m][nt] = __builtin_amdgcn_mfma_f32_16x16x32_bf16(pa[m][0], vb0, acc[m][nt], 0, 0, 0);
                acc[m][nt] = __builtin_amdgcn_mfma_f32_16x16x32_bf16(pa[m][1], vb1, acc[m][nt], 0, 0, 0);
            }
        }
    }

    const long obase = ((long)b * SEQ + qt * 128 + w * 32) * EDIM + h * 64;
    #pragma unroll
    for (int m = 0; m < 2; ++m)
        #pragma unroll
        for (int nt = 0; nt < 4; ++nt)
            #pragma unroll
            for (int r = 0; r < 4; ++r) {
                float v = acc[m][nt][r] / li[m][r];
                Out[obase + (long)(m * 16 + qrow + r) * EDIM + nt * 16 + lrow] = (bf16)v;
            }
}

// ---------------- launcher ----------------
extern "C" void kernel_launch(void* const* d_in, const int* in_sizes, int n_in,
                              void* d_out, int out_size, void* d_ws, size_t ws_size,
                              hipStream_t stream) {
    const float* x    = (const float*)d_in[0];
    // d_in[1] = attention_mask (always causal tril; handled analytically)
    const float* fr   = (const float*)d_in[2];
    const float* wqkv = (const float*)d_in[3];
    const float* wo   = (const float*)d_in[4];
    const float* w1   = (const float*)d_in[5];
    const float* w2   = (const float*)d_in[6];
    const float* w3   = (const float*)d_in[7];
    const float* anw  = (const float*)d_in[8];
    const float* fnw  = (const float*)d_in[9];
    float* out = (float*)d_out;

    // ---- workspace budget (aliased layout), ~252 MiB ----
    const size_t SZ_WQKV = (size_t)QKVN * EDIM;     // 6291456
    const size_t SZ_WO   = (size_t)EDIM * EDIM;     // 4194304
    const size_t SZ_WFF  = (size_t)FF * EDIM;       // 16777216
    const size_t B_WQKV  = SZ_WQKV * 2;             // 12.6 MB
    const size_t B_WO    = SZ_WO * 2;               //  8.4 MB
    const size_t B_WFF   = SZ_WFF * 2;              // 33.6 MB
    const size_t B_HATTN = (size_t)NTOK * EDIM * 2; // 16.8 MB
    const size_t B_QKV   = (size_t)NTOK * QKVN * 2; // 25.2 MB
    const size_t B_SCR   = (size_t)NTOK * EDIM * 4; // 33.6 MB (h2 fp32; aliases Q/K/Vt)
    const size_t B_FF1   = (size_t)NTOK * FF * 2;   // 67.1 MB
    const size_t NEED = B_WQKV + B_WO + 3 * B_WFF + B_HATTN + B_QKV + B_SCR + B_FF1;
    if (ws_size < NEED) return;   // diagnostic: clean absmax-fail instead of GPU fault

    char* ws = (char*)d_ws;
    size_t off = 0;
    auto alloc = [&](size_t bytes) -> void* {
        void* p = ws + off;
        off += (bytes + 255) & ~(size_t)255;
        return p;
    };
    bf16* wqkv_b = (bf16*)alloc(B_WQKV);
    bf16* wo_b   = (bf16*)alloc(B_WO);
    bf16* w1_b   = (bf16*)alloc(B_WFF);
    bf16* w3_b   = (bf16*)alloc(B_WFF);
    bf16* w2_b   = (bf16*)alloc(B_WFF);
    bf16* h_attn = (bf16*)alloc(B_HATTN);           // h, then attn_out
    bf16* qkv_g  = (bf16*)alloc(B_QKV);             // qkv, then g
    char* scr    = (char*)alloc(B_SCR);             // Q/K/Vt region, then h2
    bf16* Qb  = (bf16*)scr;                                         // 16.8 MB
    bf16* Kb  = (bf16*)(scr + (size_t)BATCH * NH * SEQ * HD * 2);   //  4.2 MB
    bf16* Vtb = (bf16*)(scr + (size_t)BATCH * (NH + NKV) * SEQ * HD * 2); // 4.2 MB
    float* h2 = (float*)scr;                        // aliases Q/K/Vt (dead by then)
    bf16* ff1 = (bf16*)alloc(B_FF1);                // u, then act (in-place SwiGLU)
    bf16* g_b = qkv_g;                              // reuse (qkv dead after preps)

    // 1. weights -> bf16
    cvt_f32_bf16<<<512, 256, 0, stream>>>(wqkv, wqkv_b, (long)(SZ_WQKV / 4));
    cvt_f32_bf16<<<512, 256, 0, stream>>>(wo,   wo_b,   (long)(SZ_WO / 4));
    cvt_f32_bf16<<<512, 256, 0, stream>>>(w1,   w1_b,   (long)(SZ_WFF / 4));
    cvt_f32_bf16<<<512, 256, 0, stream>>>(w3,   w3_b,   (long)(SZ_WFF / 4));
    cvt_f32_bf16<<<512, 256, 0, stream>>>(w2,   w2_b,   (long)(SZ_WFF / 4));
    // 2. h = rmsnorm(x) * attn_norm_w  (bf16)
    rmsnorm_bf16<<<NTOK, 256, 0, stream>>>(x, anw, h_attn);
    // 3. qkv = h @ w_qkv^T  (bf16 out)
    gemm_nt<1><<<dim3(QKVN / 128, NTOK / 128), 256, 0, stream>>>(
        h_attn, wqkv_b, qkv_g, nullptr, NTOK, QKVN, EDIM);
    // 4. RoPE + layout prep
    rope_prep<<<NTOK, 256, 0, stream>>>(qkv_g, fr, Qb, Kb);
    v_prep<<<BATCH * NKV * (SEQ / 64), 256, 0, stream>>>(qkv_g, Vtb);
    // 5. attention -> attn_out (bf16, [4096,2048]); 128 q-rows per block
    attn_fwd<<<dim3(SEQ / 128, BATCH * NH), 256, 0, stream>>>(Qb, Kb, Vtb, h_attn);
    // 6. h2 = x + attn_out @ w_o^T  (fp32; h2 aliases dead Q/K/Vt)
    gemm_nt<2><<<dim3(EDIM / 128, NTOK / 128), 256, 0, stream>>>(
        h_attn, wo_b, h2, x, NTOK, EDIM, EDIM);
    // 7. g = rmsnorm(h2) * ff_norm_w (bf16)
    rmsnorm_bf16<<<NTOK, 256, 0, stream>>>(h2, fnw, g_b);
    // 8. u = g @ w1^T (bf16), then act = silu(u) * (g @ w3^T) in-place over ff1
    gemm_nt<1><<<dim3(FF / 128, NTOK / 128), 256, 0, stream>>>(
        g_b, w1_b, ff1, nullptr, NTOK, FF, EDIM);
    gemm_nt<3><<<dim3(FF / 128, NTOK / 128), 256, 0, stream>>>(
        g_b, w3_b, ff1, nullptr, NTOK, FF, EDIM);
    // 9. out = h2 + act @ w2^T  (fp32)
    gemm_nt<2><<<dim3(EDIM / 128, NTOK / 128), 256, 0, stream>>>(
        ff1, w2_b, out, h2, NTOK, EDIM, FF);
    (void)in_sizes; (void)n_in; (void)out_size; (void)ws_size;
}